// Round 1
// 79.382 us; speedup vs baseline: 1.0875x; 1.0875x over previous
//
#include <hip/hip_runtime.h>
#include <stdint.h>

#define BATCH 1024
#define DIM 768

typedef unsigned long long u64;
typedef __attribute__((ext_vector_type(8))) short short8;  // 8 bf16 = 4 VGPRs
typedef __attribute__((ext_vector_type(4))) float f32x4;

// Workspace layout (bytes):
//   [0]      u64   hashes[1024]        (8 KB)
//   [8192]   int   counter
//   [12288]  float pmax[1024*4]        (16 KB)  per-row per-chunk max
//   [28672]  float psum[1024*4]        (16 KB)  per-row per-chunk sumexp
//   [45056]  float lval[1024]          (4 KB)   exact fp32 label logit per row
//   [49152]  ushort txtB[1024*768]     (1.5 MB) bf16, MFMA B-frag order
// B-frag order: off(col,k) = ((k>>5)*64 + (col>>4))*512 + ((k>>3)&3)*128
//                            + (col&15)*8 + (k&7)
#define WS_CNT   8192
#define WS_PMAX 12288
#define WS_PSUM 28672
#define WS_LVAL 45056
#define WS_TXTB 49152

__device__ __forceinline__ unsigned short to_bf16(float x) {
    unsigned int u = __float_as_uint(x);
    return (unsigned short)((u + 0x7FFFu + ((u >> 16) & 1u)) >> 16);  // RNE
}

// ---------------------------------------------------------------------------
// K1: txt fp32 -> bf16 B-frag order + img row hashes + zero counter.
// 256 blocks x 256 threads (unchanged from baseline except acc removal).
// ---------------------------------------------------------------------------
__global__ __launch_bounds__(256) void prep_kernel(
        const float* __restrict__ img, const float* __restrict__ txt,
        u64* __restrict__ hashes, int* __restrict__ counter,
        unsigned short* __restrict__ txtB) {
    if (blockIdx.x == 0 && threadIdx.x == 0) { *counter = 0; }
    const int wave = threadIdx.x >> 6;
    const int lane = threadIdx.x & 63;

    for (int i = wave; i < 6; i += 4) {
        const int G  = blockIdx.x * 6 + i;
        const int tt = G / 24;        // col-tile 0..63
        const int g  = G - tt * 24;   // k-group 0..23
        const int col = tt * 16 + (lane & 15);
        const int k0  = g * 32 + (lane >> 4) * 8;
        const float4 va = *(const float4*)(txt + (size_t)col * DIM + k0);
        const float4 vb = *(const float4*)(txt + (size_t)col * DIM + k0 + 4);
        short8 hv = {(short)to_bf16(va.x), (short)to_bf16(va.y),
                     (short)to_bf16(va.z), (short)to_bf16(va.w),
                     (short)to_bf16(vb.x), (short)to_bf16(vb.y),
                     (short)to_bf16(vb.z), (short)to_bf16(vb.w)};
        *(short8*)(txtB + (size_t)(g * 64 + tt) * 512 + lane * 8) = hv;
    }

    // img row hash (order-independent positional hash; exact-verify later)
    const int row = blockIdx.x * 4 + wave;
    const float4* rp = (const float4*)(img + (size_t)row * DIM);
    u64 h = 0;
#pragma unroll
    for (int c = 0; c < 3; ++c) {
        float4 v = rp[c * 64 + lane];
        int p = c * 256 + lane * 4;
        h += ((u64)__float_as_uint(v.x) + 0x9E3779B97F4A7C15ULL) * (u64)(2 * p + 1);
        h += ((u64)__float_as_uint(v.y) + 0x9E3779B97F4A7C15ULL) * (u64)(2 * p + 3);
        h += ((u64)__float_as_uint(v.z) + 0x9E3779B97F4A7C15ULL) * (u64)(2 * p + 5);
        h += ((u64)__float_as_uint(v.w) + 0x9E3779B97F4A7C15ULL) * (u64)(2 * p + 7);
    }
#pragma unroll
    for (int m = 32; m; m >>= 1) h += __shfl_xor(h, m, 64);
    if (lane == 0) hashes[row] = h;
}

// ---------------------------------------------------------------------------
// K2 (fused): MFMA GEMM + per-row per-chunk softmax partials + label scan +
// exact fp32 label logit + last-block chunk-combine + mean.
// 256 blocks x 1024 thr. Block = 16 rows x 256 cols (row-group b>>2, chunk
// b&3). Waves 0..3 additionally own row j = r0 + chunk*4 + wave for the
// label/lval work (bijection over 1024 rows across the 256 blocks).
// Cross-block publication of pmax/psum/lval uses device-scope atomicExch
// (executes at the coherent point -> no dependence on XCD-L2 writeback);
// the last block (threadfence + counter pattern, proven in baseline) does
// the tiny combine.
// ---------------------------------------------------------------------------
__global__ __launch_bounds__(1024) void gemm_fused(
        const float* __restrict__ img, const float* __restrict__ txt,
        const float* __restrict__ scale_p, const unsigned short* __restrict__ txtB,
        const u64* __restrict__ hashes,
        float* __restrict__ pmax, float* __restrict__ psum,
        float* __restrict__ lval, int* __restrict__ counter,
        float* __restrict__ out) {
    __shared__ unsigned short Ahi[16 * DIM];   // 24 KB, A-frag order
    __shared__ float logitsS[16 * 260];        // 16.6 KB (+4 pad vs bank stride)
    __shared__ int isLast;
    __shared__ float part[16];

    const int tid  = threadIdx.x;
    const int wave = tid >> 6;
    const int lane = tid & 63;
    const int quad = lane >> 4;
    const int l15  = lane & 15;
    const int r0    = (blockIdx.x >> 2) * 16;
    const int chunk = blockIdx.x & 3;

    // stage A: wave w converts img row r0+w into frag order
    {
        const float* ir = img + (size_t)(r0 + wave) * DIM;
#pragma unroll
        for (int j = 0; j < 12; ++j) {
            const int k = lane + j * 64;
            Ahi[((k >> 3) * 16 + wave) * 8 + (k & 7)] = to_bf16(ir[k]);
        }
    }
    __syncthreads();

    // k-loop: wave's global col-tile t, one MFMA per 32-k step (unchanged)
    const int t = chunk * 16 + wave;
    const int foff = quad * 128 + l15 * 8;
    f32x4 acc = {0.f, 0.f, 0.f, 0.f};
#pragma unroll
    for (int kk = 0; kk < 24; ++kk) {
        const short8 a = *(const short8*)&Ahi[kk * 512 + foff];
        const short8 b = *(const short8*)(txtB + (size_t)(kk * 64 + t) * 512 + foff);
        acc = __builtin_amdgcn_mfma_f32_16x16x32_bf16(a, b, acc, 0, 0, 0);
    }

    // C layout: col = l15, row = quad*4 + r  [verified baseline, absmax 0.0]
    const float scale = scale_p[0];
#pragma unroll
    for (int r = 0; r < 4; ++r)
        logitsS[(quad * 4 + r) * 260 + wave * 16 + l15] = scale * acc[r];
    __syncthreads();

    // per-row partials: wave w = row w; 4 floats/lane over 256 cols (unchanged
    // math; publication switched to device-scope atomicExch)
    {
        const float4 f = *(const float4*)&logitsS[wave * 260 + lane * 4];
        float mx = fmaxf(fmaxf(f.x, f.y), fmaxf(f.z, f.w));
#pragma unroll
        for (int s = 32; s; s >>= 1) mx = fmaxf(mx, __shfl_xor(mx, s, 64));
        float sum = __expf(f.x - mx) + __expf(f.y - mx) +
                    __expf(f.z - mx) + __expf(f.w - mx);
#pragma unroll
        for (int s = 32; s; s >>= 1) sum += __shfl_xor(sum, s, 64);
        if (lane == 0) {
            atomicExch(&pmax[(r0 + wave) * 4 + chunk], mx);
            atomicExch(&psum[(r0 + wave) * 4 + chunk], sum);
        }
    }

    // designated label work: waves 0..3 handle row j = r0 + chunk*4 + wave.
    // Branch-free hash scan: 16 unconditional independent loads -> one L2
    // latency, then a single wave-min; exact-verify rejects hash collisions.
    if (wave < 4) {
        const int j = r0 + chunk * 4 + wave;
        const u64 hj = hashes[j];
        int lo = -1;
        int label = j;
        for (;;) {
            int cand = BATCH;
#pragma unroll
            for (int it = 0; it < 16; ++it) {
                const int i = lane + it * 64;          // always < 1024, in-bounds
                const u64 h = hashes[i];
                if (i < j && i > lo && h == hj) cand = min(cand, i);
            }
#pragma unroll
            for (int s = 32; s; s >>= 1) cand = min(cand, __shfl_xor(cand, s, 64));
            if (cand >= j) break;                      // no candidate -> label = j
            // exact verify rows cand vs j
            const float4* rpm = (const float4*)(img + (size_t)cand * DIM);
            const float4* rpj = (const float4*)(img + (size_t)j * DIM);
            bool eq = true;
#pragma unroll
            for (int c = 0; c < 3; ++c) {
                float4 vm = rpm[c * 64 + lane];
                float4 vj = rpj[c * 64 + lane];
                eq = eq && (vm.x == vj.x) && (vm.y == vj.y) &&
                     (vm.z == vj.z) && (vm.w == vj.w);
            }
            if (__all(eq)) { label = cand; break; }
            lo = cand;                                 // false positive: rescan above it
        }

        // exact fp32 label logit: scale * dot(img[j], txt[label]) — identical
        // expression/order to baseline final_kernel
        const float4* aj = (const float4*)(img + (size_t)j * DIM);
        const float4* bl = (const float4*)(txt + (size_t)label * DIM);
        float s = 0.0f;
#pragma unroll
        for (int c = 0; c < 3; ++c) {
            const float4 va = aj[c * 64 + lane];
            const float4 vb = bl[c * 64 + lane];
            s += va.x * vb.x + va.y * vb.y + va.z * vb.z + va.w * vb.w;
        }
#pragma unroll
        for (int m = 32; m; m >>= 1) s += __shfl_xor(s, m, 64);
        if (lane == 0) atomicExch(&lval[j], scale * s);
    }

    // last-block tail (no spin; identical pattern to baseline's out-write)
    __syncthreads();
    if (tid == 0) {
        __threadfence();
        isLast = (atomicAdd(counter, 1) == (int)gridDim.x - 1) ? 1 : 0;
    }
    __syncthreads();
    if (!isLast) return;
    __threadfence();   // acquire: invalidate local caches before reading others' data

    // thread t combines row t: lse from 4 chunk partials (identical math to
    // baseline final_kernel), minus exact label logit; block-reduce the mean.
    {
        const float4 m4 = *(const float4*)&pmax[tid * 4];
        const float4 s4 = *(const float4*)&psum[tid * 4];
        const float lv = lval[tid];
        const float gmax = fmaxf(fmaxf(m4.x, m4.y), fmaxf(m4.z, m4.w));
        const float ss = s4.x * __expf(m4.x - gmax) + s4.y * __expf(m4.y - gmax)
                       + s4.z * __expf(m4.z - gmax) + s4.w * __expf(m4.w - gmax);
        float loss = gmax + __logf(ss) - lv;
#pragma unroll
        for (int m = 32; m; m >>= 1) loss += __shfl_xor(loss, m, 64);
        if (lane == 0) part[wave] = loss;
        __syncthreads();
        if (tid == 0) {
            float tot = 0.0f;
#pragma unroll
            for (int w = 0; w < 16; ++w) tot += part[w];
            out[0] = tot * (1.0f / BATCH);
        }
    }
}

extern "C" void kernel_launch(void* const* d_in, const int* in_sizes, int n_in,
                              void* d_out, int out_size, void* d_ws, size_t ws_size,
                              hipStream_t stream) {
    const float* img   = (const float*)d_in[0];
    const float* txt   = (const float*)d_in[1];
    const float* scale = (const float*)d_in[2];
    float* out = (float*)d_out;
    char* ws = (char*)d_ws;

    u64*   hashes  = (u64*)ws;
    int*   counter = (int*)(ws + WS_CNT);
    float* pmax    = (float*)(ws + WS_PMAX);
    float* psum    = (float*)(ws + WS_PSUM);
    float* lval    = (float*)(ws + WS_LVAL);
    unsigned short* txtB = (unsigned short*)(ws + WS_TXTB);

    prep_kernel<<<256, 256, 0, stream>>>(img, txt, hashes, counter, txtB);
    gemm_fused<<<256, 1024, 0, stream>>>(img, txt, scale, txtB, hashes,
                                         pmax, psum, lval, counter, out);
}